// Round 14
// baseline (2108.956 us; speedup 1.0000x reference)
//
#include <hip/hip_runtime.h>
#include <cstddef>

#define DI __device__ __forceinline__

constexpr int NB  = 8;
constexpr int NP  = 4096;
constexpr int KNN = 20;

DI float lrelu(float z) { return z >= 0.f ? z : 0.2f * z; }

// ---------------- prep: transpose input to point-major xt[b][n][4] + xx ----------------
__global__ void k_prep(const float* __restrict__ xin, float* __restrict__ xt,
                       float* __restrict__ xx) {
  int t = blockIdx.x * blockDim.x + threadIdx.x;           // bn
  int b = t >> 12, n = t & (NP - 1);
  float c0 = xin[(0 * NB + b) * NP + n];
  float c1 = xin[(1 * NB + b) * NP + n];
  float c2 = xin[(2 * NB + b) * NP + n];
  *reinterpret_cast<float4*>(xt + (size_t)t * 4) = make_float4(c0, c1, c2, 0.f);
  xx[t] = c0 * c0 + c1 * c1 + c2 * c2;
}

// ---------------- xx for C-channel point-major ----------------
template<int C>
__global__ void k_xx(const float* __restrict__ X, float* __restrict__ xx) {
  int bn = blockIdx.x * blockDim.x + threadIdx.x;
  float s = 0.f;
#pragma unroll
  for (int c = 0; c < C; c += 4) {
    float4 a = *reinterpret_cast<const float4*>(X + (size_t)bn * C + c);
    s += a.x * a.x + a.y * a.y + a.z * a.z + a.w * a.w;
  }
  xx[bn] = s;
}

// ---------------- knn v6: plane-major candidates; optional 2-wave/row split ----------
// Block = 4 waves. HALF=false: 4 rows, wave owns all 64 slots (round-13 proven path).
// HALF=true: 2 rows x 2 halves (even/odd chunks); wave owns 32 slots; the two
// sorted 20-lists per row are rank-merged in LDS ((val desc, idx asc), exact).
// All LDS patterns lane-contiguous float4 (measured 0-conflict class).
template<int C, int P, bool HALF>
__global__ __launch_bounds__(256) void k_knn(const float* __restrict__ Xq,
                                             const float* __restrict__ XT,
                                             const float* __restrict__ xx,
                                             int* __restrict__ idxout) {
  constexpr int CH = NP / P;                // chunks
  constexpr int SL = P / 64;                // slots per chunk
  constexpr int F4 = C / 4;                 // float4 per point
  constexpr int LD = P * F4 / 256;          // staging float4 loads per thread (=4)
  constexpr int NSLOT = HALF ? 32 : 64;     // slots owned per wave
  constexpr int NG = NSLOT / 16;            // selection groups
  __shared__ float4 lds4[2 * P * F4];
  __shared__ float mv[4][20];
  __shared__ int   mi[4][20];

  int wv   = threadIdx.x >> 6;
  int lane = threadIdx.x & 63;
  int r, h, row;
  if (HALF) { r = wv >> 1; h = wv & 1; row = blockIdx.x * 2 + r; }
  else      { r = wv;      h = 0;      row = blockIdx.x * 4 + wv; }
  int b = row >> 12, n = row & (NP - 1);
  const float*  Xqb  = Xq + (size_t)b * NP * C;
  const float4* srcT = reinterpret_cast<const float4*>(XT + (size_t)b * NP * C);
  const float*  xxb  = xx + (size_t)b * NP;

  float q[C];
#pragma unroll
  for (int c = 0; c < C; c += 4) {
    float4 a = *reinterpret_cast<const float4*>(Xqb + (size_t)n * C + c);
    q[c] = a.x; q[c + 1] = a.y; q[c + 2] = a.z; q[c + 3] = a.w;
  }
  float xxn = xxb[n];

  float v[NSLOT];
  float gv[NG]; int gj[NG];                 // gj holds GLOBAL candidate index
#pragma unroll
  for (int g = 0; g < NG; ++g) { gv[g] = -3.0e38f; gj[g] = 0; }

  // prologue: prefetch chunk 0 (plane u/P, point u%P)
  float4 nxt[LD];
#pragma unroll
  for (int i = 0; i < LD; ++i) {
    int u = i * 256 + (int)threadIdx.x;
    nxt[i] = srcT[(size_t)(u / P) * NP + (u % P)];
  }

#pragma unroll
  for (int ch = 0; ch < CH; ++ch) {
    float4* B = lds4 + (ch & 1) * (P * F4);
#pragma unroll
    for (int i = 0; i < LD; ++i)
      B[i * 256 + (int)threadIdx.x] = nxt[i];   // linear, stride-1 writes
    __syncthreads();                        // all writes to buf[ch&1] visible
    if (ch + 1 < CH) {                      // issue next chunk AFTER barrier
#pragma unroll
      for (int i = 0; i < LD; ++i) {
        int u = i * 256 + (int)threadIdx.x;
        nxt[i] = srcT[(size_t)(u / P) * NP + (size_t)(ch + 1) * P + (u % P)];
      }
    }
    if (!HALF || ((ch & 1) == h)) {
#pragma unroll
      for (int sl = 0; sl < SL; ++sl) {
        const int sg   = ch * SL + sl;                       // global slot
        const int lidx = HALF ? ((ch >> 1) * SL + sl) : sg;  // compile-time
        int p = sl * 64 + lane;
        int cand = sg * 64 + lane;
        float xxm = xxb[cand];
        float dp[4] = {0.f, 0.f, 0.f, 0.f};
#pragma unroll
        for (int cg = 0; cg < F4; ++cg) {
          float4 a = B[cg * P + p];           // lane-contiguous reads
          dp[cg & 3] = fmaf(q[cg * 4 + 0], a.x, dp[cg & 3]);
          dp[cg & 3] = fmaf(q[cg * 4 + 1], a.y, dp[cg & 3]);
          dp[cg & 3] = fmaf(q[cg * 4 + 2], a.z, dp[cg & 3]);
          dp[cg & 3] = fmaf(q[cg * 4 + 3], a.w, dp[cg & 3]);
        }
        float dot = (dp[0] + dp[1]) + (dp[2] + dp[3]);
        float val = 2.f * dot - xxm - xxn;    // pd = 2*dot - xxm - xxn
        v[lidx] = val;
        const int g = lidx >> 4;              // compile-time
        bool better = val > gv[g];            // ascending cand order: smallest idx wins ties
        gv[g] = better ? val  : gv[g];
        gj[g] = better ? cand : gj[g];
      }
    }
    // single barrier per chunk: writes to this buffer (iter ch+2) can only start
    // after all waves passed barrier(ch+1), i.e. after compute(ch) finished.
  }

  // ---- per-wave exact top-20 over owned slots ----
  float myv = -3.0e38f; int myi = 0;
#pragma unroll 1
  for (int t = 0; t < KNN; ++t) {
    float bv = gv[0]; int bi = gj[0];
#pragma unroll
    for (int g = 1; g < NG; ++g) {
      bool bet = gv[g] > bv;                 // higher g => larger idx; > keeps smaller
      bv = bet ? gv[g] : bv;
      bi = bet ? gj[g] : bi;
    }
#pragma unroll
    for (int off = 32; off >= 1; off >>= 1) {
      float ov = __shfl_xor(bv, off);
      int   oi = __shfl_xor(bi, off);
      bool bet = (ov > bv) || (ov == bv && oi < bi);
      bv = bet ? ov : bv;
      bi = bet ? oi : bi;
    }
    if (lane == t) { myv = bv; myi = bi; }
    if (lane == (bi & 63)) {                 // winner lane: remove + rebuild group
      int lg = bi >> 6;                      // global slot
      int lw = HALF ? (((lg / SL) >> 1) * SL + (lg % SL)) : lg;   // local slot
      int g  = lw >> 4;
#pragma unroll
      for (int G = 0; G < NG; ++G) {
        if (g == G) {
          float nv = -3.0e38f; int nj = 0;
#pragma unroll
          for (int jj = G * 16; jj < G * 16 + 16; ++jj) {
            v[jj] = (jj == lw) ? -3.4e38f : v[jj];
            bool bet = v[jj] > nv;
            nv = bet ? v[jj] : nv;
            nj = bet ? jj : nj;
          }
          gv[G] = nv;
          int sg = HALF ? (((nj / SL) * 2 + h) * SL + (nj % SL)) : nj;
          gj[G] = (sg << 6) | lane;
        }
      }
    }
  }

  if (!HALF) {
    if (lane < KNN) idxout[(size_t)row * KNN + lane] = myi;
  } else {
    if (lane < KNN) { mv[wv][lane] = myv; mi[wv][lane] = myi; }
    __syncthreads();
    // rank-merge the two sorted 20-lists of row (wave wv<2 merges row wv)
    if (wv < 2) {
      const float* fv = &mv[wv * 2][0];      // lists [2][20] contiguous
      const int*   fi = &mi[wv * 2][0];
      float ev = (lane < 40) ? fv[lane] : -3.4e38f;
      int   ei = (lane < 40) ? fi[lane] : -1;
      int rk = 0;
#pragma unroll 4
      for (int j = 0; j < 40; ++j) {
        float jv = fv[j]; int ji = fi[j];
        rk += ((jv > ev) || (jv == ev && ji < ei)) ? 1 : 0;
      }
      int orow = blockIdx.x * 2 + wv;
      if (lane < 40 && rk < KNN) idxout[(size_t)orow * KNN + rk] = ei;
    }
  }
}

// ---------------- deterministic block reduce: CG channels of (s,ss) ----------------
template<int CG>
DI void block_reduce_write(float (&s)[CG], float (&ss)[CG], float* red, float* out) {
#pragma unroll
  for (int o = 0; o < CG; ++o) {
#pragma unroll
    for (int off = 32; off >= 1; off >>= 1) {
      s[o]  += __shfl_xor(s[o],  off);
      ss[o] += __shfl_xor(ss[o], off);
    }
  }
  int lane = threadIdx.x & 63, wv = threadIdx.x >> 6;
  if (lane == 0) {
#pragma unroll
    for (int o = 0; o < CG; ++o) {
      red[wv * 2 * CG + o]      = s[o];
      red[wv * 2 * CG + CG + o] = ss[o];
    }
  }
  __syncthreads();
  if ((int)threadIdx.x < 2 * CG) {
    out[threadIdx.x] = red[0 * 2 * CG + threadIdx.x] + red[1 * 2 * CG + threadIdx.x] +
                       red[2 * 2 * CG + threadIdx.x] + red[3 * 2 * CG + threadIdx.x];
  }
}

// ---------------- BN finalize (parallel, deterministic) ----------------
template<int COUT, int CG, int OG, int KG>
__global__ void k_bnfin(const float* __restrict__ parts, const float* __restrict__ g,
                        const float* __restrict__ bb, float* __restrict__ bnp) {
  constexpr int G = 256 / COUT;
  __shared__ float red[512];
  int tid = threadIdx.x;
  int sub = tid / COUT, o = tid % COUT;
  int og = o / CG, oo = o % CG;
  float S = 0.f, SS = 0.f;
  for (int z = 0; z < KG; ++z)
    for (int x = sub; x < 128; x += G) {
      size_t p = ((size_t)(z * OG + og) * 128 + x) * (2 * CG);
      S  += parts[p + oo];
      SS += parts[p + CG + oo];
    }
  red[tid] = S; red[256 + tid] = SS;
  __syncthreads();
  if (tid < COUT) {
    S = 0.f; SS = 0.f;
#pragma unroll
    for (int gg = 0; gg < G; ++gg) { S += red[gg * COUT + tid]; SS += red[256 + gg * COUT + tid]; }
    const float cnt = (float)NB * NP * KNN;
    float m   = S / cnt;
    float var = SS / cnt - m * m;
    float sc  = g[tid] / sqrtf(var + 1e-5f);
    bnp[tid]        = sc;
    bnp[COUT + tid] = bb[tid] - m * sc;
  }
}

// ================= conv1: Cin=6, Cout=16 (all 16 ch/block, base trick) =================
__global__ __launch_bounds__(256) void k_stats1(const float* __restrict__ xt,
    const int* __restrict__ idx1, const float* __restrict__ w, float* __restrict__ parts) {
  __shared__ float red[4 * 32];
  int bn = blockIdx.x * 256 + threadIdx.x;
  int b = bn >> 12;
  float4 ctr = *reinterpret_cast<const float4*>(xt + (size_t)bn * 4);
  float base[16], s[16], ss[16];
#pragma unroll
  for (int o = 0; o < 16; ++o) {
    const float* wo = w + o * 6;
    base[o] = (wo[3] - wo[0]) * ctr.x + (wo[4] - wo[1]) * ctr.y + (wo[5] - wo[2]) * ctr.z;
    s[o] = 0.f; ss[o] = 0.f;
  }
  const int* ip = idx1 + (size_t)bn * KNN + blockIdx.z * 10;
  for (int kk = 0; kk < 10; ++kk) {
    int m = ip[kk];
    float4 nb = *reinterpret_cast<const float4*>(xt + (size_t)(b * NP + m) * 4);
#pragma unroll
    for (int o = 0; o < 16; ++o) {
      const float* wo = w + o * 6;
      float y = fmaf(wo[0], nb.x, fmaf(wo[1], nb.y, fmaf(wo[2], nb.z, base[o])));
      s[o] += y; ss[o] = fmaf(y, y, ss[o]);
    }
  }
  size_t p = ((size_t)blockIdx.z * 128 + blockIdx.x) * 32;
  block_reduce_write<16>(s, ss, red, parts + p);
}

// apply1 also writes plane-major x1mT (fused transpose)
__global__ __launch_bounds__(256) void k_apply1(const float* __restrict__ xt,
    const int* __restrict__ idx1, const float* __restrict__ w, const float* __restrict__ bnp,
    float* __restrict__ x1m, float* __restrict__ x1mT) {
  int bn = blockIdx.x * 256 + threadIdx.x;
  int og = blockIdx.y * 8;
  int b = bn >> 12, pidx = bn & (NP - 1);
  float4 ctr = *reinterpret_cast<const float4*>(xt + (size_t)bn * 4);
  float base[8], mx[8];
#pragma unroll
  for (int o = 0; o < 8; ++o) {
    const float* wo = w + (og + o) * 6;
    base[o] = (wo[3] - wo[0]) * ctr.x + (wo[4] - wo[1]) * ctr.y + (wo[5] - wo[2]) * ctr.z;
    mx[o] = -3.0e38f;
  }
  const int* ip = idx1 + (size_t)bn * KNN;
  for (int k = 0; k < KNN; ++k) {
    int m = ip[k];
    float4 nb = *reinterpret_cast<const float4*>(xt + (size_t)(b * NP + m) * 4);
#pragma unroll
    for (int o = 0; o < 8; ++o) {
      const float* wo = w + (og + o) * 6;
      float y = fmaf(wo[0], nb.x, fmaf(wo[1], nb.y, fmaf(wo[2], nb.z, base[o])));
      mx[o] = fmaxf(mx[o], lrelu(y * bnp[og + o] + bnp[16 + og + o]));
    }
  }
#pragma unroll
  for (int o = 0; o < 8; ++o) x1m[(size_t)bn * 16 + og + o] = mx[o];
  int cg0 = og >> 2;
  float4 lo = make_float4(mx[0], mx[1], mx[2], mx[3]);
  float4 hi = make_float4(mx[4], mx[5], mx[6], mx[7]);
  reinterpret_cast<float4*>(x1mT)[(size_t)b * NP * 4 + (size_t)cg0 * NP + pidx] = lo;
  reinterpret_cast<float4*>(x1mT)[(size_t)b * NP * 4 + (size_t)(cg0 + 1) * NP + pidx] = hi;
}

// ================= conv2: Cin=38, Cout=32, CG=8 =================
__global__ __launch_bounds__(256) void k_stats2(const float* __restrict__ xt,
    const float* __restrict__ x1m, const int* __restrict__ idx1, const int* __restrict__ idx2,
    const float* __restrict__ w, float* __restrict__ parts) {
  __shared__ float red[4 * 16];
  int bn = blockIdx.x * 256 + threadIdx.x;
  int og = blockIdx.y * 8;
  int b = bn >> 12;
  float4 ctr3 = *reinterpret_cast<const float4*>(xt + (size_t)bn * 4);
  float base[8], s[8], ss[8];
#pragma unroll
  for (int o = 0; o < 8; ++o) {
    const float* wo = w + (og + o) * 38;
    base[o] = (wo[3] - wo[0]) * ctr3.x + (wo[4] - wo[1]) * ctr3.y + (wo[5] - wo[2]) * ctr3.z;
    s[o] = 0.f; ss[o] = 0.f;
  }
#pragma unroll
  for (int cg = 0; cg < 4; ++cg) {
    float4 a = *reinterpret_cast<const float4*>(x1m + (size_t)bn * 16 + cg * 4);
#pragma unroll
    for (int o = 0; o < 8; ++o) {
      const float* wo = w + (og + o) * 38;
      base[o] += (wo[22 + cg*4] - wo[6 + cg*4]) * a.x + (wo[23 + cg*4] - wo[7 + cg*4]) * a.y +
                 (wo[24 + cg*4] - wo[8 + cg*4]) * a.z + (wo[25 + cg*4] - wo[9 + cg*4]) * a.w;
    }
  }
  const int* i1 = idx1 + (size_t)bn * KNN + blockIdx.z * 10;
  const int* i2 = idx2 + (size_t)bn * KNN + blockIdx.z * 10;
  for (int kk = 0; kk < 10; ++kk) {
    int m1 = i1[kk], m2 = i2[kk];
    float4 nb3 = *reinterpret_cast<const float4*>(xt + (size_t)(b * NP + m1) * 4);
    float4 a0 = *reinterpret_cast<const float4*>(x1m + (size_t)(b * NP + m2) * 16 + 0);
    float4 a1 = *reinterpret_cast<const float4*>(x1m + (size_t)(b * NP + m2) * 16 + 4);
    float4 a2 = *reinterpret_cast<const float4*>(x1m + (size_t)(b * NP + m2) * 16 + 8);
    float4 a3 = *reinterpret_cast<const float4*>(x1m + (size_t)(b * NP + m2) * 16 + 12);
#pragma unroll
    for (int o = 0; o < 8; ++o) {
      const float* wo = w + (og + o) * 38;
      float y = base[o];
      y = fmaf(wo[0], nb3.x, y); y = fmaf(wo[1], nb3.y, y); y = fmaf(wo[2], nb3.z, y);
      y = fmaf(wo[6],  a0.x, y); y = fmaf(wo[7],  a0.y, y); y = fmaf(wo[8],  a0.z, y); y = fmaf(wo[9],  a0.w, y);
      y = fmaf(wo[10], a1.x, y); y = fmaf(wo[11], a1.y, y); y = fmaf(wo[12], a1.z, y); y = fmaf(wo[13], a1.w, y);
      y = fmaf(wo[14], a2.x, y); y = fmaf(wo[15], a2.y, y); y = fmaf(wo[16], a2.z, y); y = fmaf(wo[17], a2.w, y);
      y = fmaf(wo[18], a3.x, y); y = fmaf(wo[19], a3.y, y); y = fmaf(wo[20], a3.z, y); y = fmaf(wo[21], a3.w, y);
      s[o] += y; ss[o] = fmaf(y, y, ss[o]);
    }
  }
  size_t p = ((size_t)(blockIdx.z * 4 + blockIdx.y) * 128 + blockIdx.x) * 16;
  block_reduce_write<8>(s, ss, red, parts + p);
}

// apply2 also writes plane-major x2mT (fused transpose)
__global__ __launch_bounds__(256) void k_apply2(const float* __restrict__ xt,
    const float* __restrict__ x1m, const int* __restrict__ idx1, const int* __restrict__ idx2,
    const float* __restrict__ w, const float* __restrict__ bnp, float* __restrict__ x2m,
    float* __restrict__ x2mT) {
  int bn = blockIdx.x * 256 + threadIdx.x;
  int og = blockIdx.y * 8;
  int b = bn >> 12, pidx = bn & (NP - 1);
  float4 ctr3 = *reinterpret_cast<const float4*>(xt + (size_t)bn * 4);
  float base[8], mx[8];
#pragma unroll
  for (int o = 0; o < 8; ++o) {
    const float* wo = w + (og + o) * 38;
    base[o] = (wo[3] - wo[0]) * ctr3.x + (wo[4] - wo[1]) * ctr3.y + (wo[5] - wo[2]) * ctr3.z;
    mx[o] = -3.0e38f;
  }
#pragma unroll
  for (int cg = 0; cg < 4; ++cg) {
    float4 a = *reinterpret_cast<const float4*>(x1m + (size_t)bn * 16 + cg * 4);
#pragma unroll
    for (int o = 0; o < 8; ++o) {
      const float* wo = w + (og + o) * 38;
      base[o] += (wo[22 + cg*4] - wo[6 + cg*4]) * a.x + (wo[23 + cg*4] - wo[7 + cg*4]) * a.y +
                 (wo[24 + cg*4] - wo[8 + cg*4]) * a.z + (wo[25 + cg*4] - wo[9 + cg*4]) * a.w;
    }
  }
  const int* i1 = idx1 + (size_t)bn * KNN;
  const int* i2 = idx2 + (size_t)bn * KNN;
  for (int k = 0; k < KNN; ++k) {
    int m1 = i1[k], m2 = i2[k];
    float4 nb3 = *reinterpret_cast<const float4*>(xt + (size_t)(b * NP + m1) * 4);
    float4 a0 = *reinterpret_cast<const float4*>(x1m + (size_t)(b * NP + m2) * 16 + 0);
    float4 a1 = *reinterpret_cast<const float4*>(x1m + (size_t)(b * NP + m2) * 16 + 4);
    float4 a2 = *reinterpret_cast<const float4*>(x1m + (size_t)(b * NP + m2) * 16 + 8);
    float4 a3 = *reinterpret_cast<const float4*>(x1m + (size_t)(b * NP + m2) * 16 + 12);
#pragma unroll
    for (int o = 0; o < 8; ++o) {
      const float* wo = w + (og + o) * 38;
      float y = base[o];
      y = fmaf(wo[0], nb3.x, y); y = fmaf(wo[1], nb3.y, y); y = fmaf(wo[2], nb3.z, y);
      y = fmaf(wo[6],  a0.x, y); y = fmaf(wo[7],  a0.y, y); y = fmaf(wo[8],  a0.z, y); y = fmaf(wo[9],  a0.w, y);
      y = fmaf(wo[10], a1.x, y); y = fmaf(wo[11], a1.y, y); y = fmaf(wo[12], a1.z, y); y = fmaf(wo[13], a1.w, y);
      y = fmaf(wo[14], a2.x, y); y = fmaf(wo[15], a2.y, y); y = fmaf(wo[16], a2.z, y); y = fmaf(wo[17], a2.w, y);
      y = fmaf(wo[18], a3.x, y); y = fmaf(wo[19], a3.y, y); y = fmaf(wo[20], a3.z, y); y = fmaf(wo[21], a3.w, y);
      mx[o] = fmaxf(mx[o], lrelu(y * bnp[og + o] + bnp[32 + og + o]));
    }
  }
#pragma unroll
  for (int o = 0; o < 8; ++o) x2m[(size_t)bn * 32 + og + o] = mx[o];
  int cg0 = og >> 2;
  float4 lo = make_float4(mx[0], mx[1], mx[2], mx[3]);
  float4 hi = make_float4(mx[4], mx[5], mx[6], mx[7]);
  reinterpret_cast<float4*>(x2mT)[(size_t)b * NP * 8 + (size_t)cg0 * NP + pidx] = lo;
  reinterpret_cast<float4*>(x2mT)[(size_t)b * NP * 8 + (size_t)(cg0 + 1) * NP + pidx] = hi;
}

// ================= convd1: Cin=32 (x1m/idx2), Cout=32, CG=8 =================
__global__ __launch_bounds__(256) void k_statsd1(const float* __restrict__ x1m,
    const int* __restrict__ idx2, const float* __restrict__ w, float* __restrict__ parts) {
  __shared__ float red[4 * 16];
  int bn = blockIdx.x * 256 + threadIdx.x;
  int og = blockIdx.y * 8;
  int b = bn >> 12;
  float base[8], s[8], ss[8];
#pragma unroll
  for (int o = 0; o < 8; ++o) { base[o] = 0.f; s[o] = 0.f; ss[o] = 0.f; }
#pragma unroll
  for (int cg = 0; cg < 4; ++cg) {
    float4 a = *reinterpret_cast<const float4*>(x1m + (size_t)bn * 16 + cg * 4);
#pragma unroll
    for (int o = 0; o < 8; ++o) {
      const float* wo = w + (og + o) * 32;
      base[o] += (wo[16 + cg*4] - wo[cg*4]) * a.x + (wo[17 + cg*4] - wo[1 + cg*4]) * a.y +
                 (wo[18 + cg*4] - wo[2 + cg*4]) * a.z + (wo[19 + cg*4] - wo[3 + cg*4]) * a.w;
    }
  }
  const int* i2 = idx2 + (size_t)bn * KNN + blockIdx.z * 10;
  for (int kk = 0; kk < 10; ++kk) {
    int m2 = i2[kk];
    float4 a0 = *reinterpret_cast<const float4*>(x1m + (size_t)(b * NP + m2) * 16 + 0);
    float4 a1 = *reinterpret_cast<const float4*>(x1m + (size_t)(b * NP + m2) * 16 + 4);
    float4 a2 = *reinterpret_cast<const float4*>(x1m + (size_t)(b * NP + m2) * 16 + 8);
    float4 a3 = *reinterpret_cast<const float4*>(x1m + (size_t)(b * NP + m2) * 16 + 12);
#pragma unroll
    for (int o = 0; o < 8; ++o) {
      const float* wo = w + (og + o) * 32;
      float y = base[o];
      y = fmaf(wo[0],  a0.x, y); y = fmaf(wo[1],  a0.y, y); y = fmaf(wo[2],  a0.z, y); y = fmaf(wo[3],  a0.w, y);
      y = fmaf(wo[4],  a1.x, y); y = fmaf(wo[5],  a1.y, y); y = fmaf(wo[6],  a1.z, y); y = fmaf(wo[7],  a1.w, y);
      y = fmaf(wo[8],  a2.x, y); y = fmaf(wo[9],  a2.y, y); y = fmaf(wo[10], a2.z, y); y = fmaf(wo[11], a2.w, y);
      y = fmaf(wo[12], a3.x, y); y = fmaf(wo[13], a3.y, y); y = fmaf(wo[14], a3.z, y); y = fmaf(wo[15], a3.w, y);
      s[o] += y; ss[o] = fmaf(y, y, ss[o]);
    }
  }
  size_t p = ((size_t)(blockIdx.z * 4 + blockIdx.y) * 128 + blockIdx.x) * 16;
  block_reduce_write<8>(s, ss, red, parts + p);
}

__global__ __launch_bounds__(256) void k_applyd1(const float* __restrict__ x1m,
    const int* __restrict__ idx2, const float* __restrict__ w, const float* __restrict__ bnp,
    float* __restrict__ xd1) {
  int bn = blockIdx.x * 256 + threadIdx.x;
  int og = blockIdx.y * 8;
  int b = bn >> 12;
  float base[8], mx[8];
#pragma unroll
  for (int o = 0; o < 8; ++o) { base[o] = 0.f; mx[o] = -3.0e38f; }
#pragma unroll
  for (int cg = 0; cg < 4; ++cg) {
    float4 a = *reinterpret_cast<const float4*>(x1m + (size_t)bn * 16 + cg * 4);
#pragma unroll
    for (int o = 0; o < 8; ++o) {
      const float* wo = w + (og + o) * 32;
      base[o] += (wo[16 + cg*4] - wo[cg*4]) * a.x + (wo[17 + cg*4] - wo[1 + cg*4]) * a.y +
                 (wo[18 + cg*4] - wo[2 + cg*4]) * a.z + (wo[19 + cg*4] - wo[3 + cg*4]) * a.w;
    }
  }
  const int* i2 = idx2 + (size_t)bn * KNN;
  for (int k = 0; k < KNN; ++k) {
    int m2 = i2[k];
    float4 a0 = *reinterpret_cast<const float4*>(x1m + (size_t)(b * NP + m2) * 16 + 0);
    float4 a1 = *reinterpret_cast<const float4*>(x1m + (size_t)(b * NP + m2) * 16 + 4);
    float4 a2 = *reinterpret_cast<const float4*>(x1m + (size_t)(b * NP + m2) * 16 + 8);
    float4 a3 = *reinterpret_cast<const float4*>(x1m + (size_t)(b * NP + m2) * 16 + 12);
#pragma unroll
    for (int o = 0; o < 8; ++o) {
      const float* wo = w + (og + o) * 32;
      float y = base[o];
      y = fmaf(wo[0],  a0.x, y); y = fmaf(wo[1],  a0.y, y); y = fmaf(wo[2],  a0.z, y); y = fmaf(wo[3],  a0.w, y);
      y = fmaf(wo[4],  a1.x, y); y = fmaf(wo[5],  a1.y, y); y = fmaf(wo[6],  a1.z, y); y = fmaf(wo[7],  a1.w, y);
      y = fmaf(wo[8],  a2.x, y); y = fmaf(wo[9],  a2.y, y); y = fmaf(wo[10], a2.z, y); y = fmaf(wo[11], a2.w, y);
      y = fmaf(wo[12], a3.x, y); y = fmaf(wo[13], a3.y, y); y = fmaf(wo[14], a3.z, y); y = fmaf(wo[15], a3.w, y);
      mx[o] = fmaxf(mx[o], lrelu(y * bnp[og + o] + bnp[32 + og + o]));
    }
  }
#pragma unroll
  for (int o = 0; o < 8; ++o) xd1[(size_t)bn * 32 + og + o] = mx[o];
}

// ================= convd2: Cin=64 (x2m/idx3), Cout=32, CG=8 =================
__global__ __launch_bounds__(256) void k_statsd2(const float* __restrict__ x2m,
    const int* __restrict__ idx3, const float* __restrict__ w, float* __restrict__ parts) {
  __shared__ float red[4 * 16];
  int bn = blockIdx.x * 256 + threadIdx.x;
  int og = blockIdx.y * 8;
  int b = bn >> 12;
  float base[8], s[8], ss[8];
#pragma unroll
  for (int o = 0; o < 8; ++o) { base[o] = 0.f; s[o] = 0.f; ss[o] = 0.f; }
#pragma unroll
  for (int cg = 0; cg < 8; ++cg) {
    float4 a = *reinterpret_cast<const float4*>(x2m + (size_t)bn * 32 + cg * 4);
#pragma unroll
    for (int o = 0; o < 8; ++o) {
      const float* wo = w + (og + o) * 64;
      base[o] += (wo[32 + cg*4] - wo[cg*4]) * a.x + (wo[33 + cg*4] - wo[1 + cg*4]) * a.y +
                 (wo[34 + cg*4] - wo[2 + cg*4]) * a.z + (wo[35 + cg*4] - wo[3 + cg*4]) * a.w;
    }
  }
  const int* i3 = idx3 + (size_t)bn * KNN + blockIdx.z * 10;
  for (int kk = 0; kk < 10; ++kk) {
    int m3 = i3[kk];
    const float* np = x2m + (size_t)(b * NP + m3) * 32;
    float4 a0 = *reinterpret_cast<const float4*>(np + 0);
    float4 a1 = *reinterpret_cast<const float4*>(np + 4);
    float4 a2 = *reinterpret_cast<const float4*>(np + 8);
    float4 a3 = *reinterpret_cast<const float4*>(np + 12);
    float4 a4 = *reinterpret_cast<const float4*>(np + 16);
    float4 a5 = *reinterpret_cast<const float4*>(np + 20);
    float4 a6 = *reinterpret_cast<const float4*>(np + 24);
    float4 a7 = *reinterpret_cast<const float4*>(np + 28);
#pragma unroll
    for (int o = 0; o < 8; ++o) {
      const float* wo = w + (og + o) * 64;
      float y = base[o];
      y = fmaf(wo[0],  a0.x, y); y = fmaf(wo[1],  a0.y, y); y = fmaf(wo[2],  a0.z, y); y = fmaf(wo[3],  a0.w, y);
      y = fmaf(wo[4],  a1.x, y); y = fmaf(wo[5],  a1.y, y); y = fmaf(wo[6],  a1.z, y); y = fmaf(wo[7],  a1.w, y);
      y = fmaf(wo[8],  a2.x, y); y = fmaf(wo[9],  a2.y, y); y = fmaf(wo[10], a2.z, y); y = fmaf(wo[11], a2.w, y);
      y = fmaf(wo[12], a3.x, y); y = fmaf(wo[13], a3.y, y); y = fmaf(wo[14], a3.z, y); y = fmaf(wo[15], a3.w, y);
      y = fmaf(wo[16], a4.x, y); y = fmaf(wo[17], a4.y, y); y = fmaf(wo[18], a4.z, y); y = fmaf(wo[19], a4.w, y);
      y = fmaf(wo[20], a5.x, y); y = fmaf(wo[21], a5.y, y); y = fmaf(wo[22], a5.z, y); y = fmaf(wo[23], a5.w, y);
      y = fmaf(wo[24], a6.x, y); y = fmaf(wo[25], a6.y, y); y = fmaf(wo[26], a6.z, y); y = fmaf(wo[27], a6.w, y);
      y = fmaf(wo[28], a7.x, y); y = fmaf(wo[29], a7.y, y); y = fmaf(wo[30], a7.z, y); y = fmaf(wo[31], a7.w, y);
      s[o] += y; ss[o] = fmaf(y, y, ss[o]);
    }
  }
  size_t p = ((size_t)(blockIdx.z * 4 + blockIdx.y) * 128 + blockIdx.x) * 16;
  block_reduce_write<8>(s, ss, red, parts + p);
}

__global__ __launch_bounds__(256) void k_applyd2(const float* __restrict__ x2m,
    const int* __restrict__ idx3, const float* __restrict__ w, const float* __restrict__ bnp,
    float* __restrict__ xd2) {
  int bn = blockIdx.x * 256 + threadIdx.x;
  int og = blockIdx.y * 8;
  int b = bn >> 12;
  float base[8], mx[8];
#pragma unroll
  for (int o = 0; o < 8; ++o) { base[o] = 0.f; mx[o] = -3.0e38f; }
#pragma unroll
  for (int cg = 0; cg < 8; ++cg) {
    float4 a = *reinterpret_cast<const float4*>(x2m + (size_t)bn * 32 + cg * 4);
#pragma unroll
    for (int o = 0; o < 8; ++o) {
      const float* wo = w + (og + o) * 64;
      base[o] += (wo[32 + cg*4] - wo[cg*4]) * a.x + (wo[33 + cg*4] - wo[1 + cg*4]) * a.y +
                 (wo[34 + cg*4] - wo[2 + cg*4]) * a.z + (wo[35 + cg*4] - wo[3 + cg*4]) * a.w;
    }
  }
  const int* i3 = idx3 + (size_t)bn * KNN;
  for (int k = 0; k < KNN; ++k) {
    int m3 = i3[k];
    const float* np = x2m + (size_t)(b * NP + m3) * 32;
    float4 a0 = *reinterpret_cast<const float4*>(np + 0);
    float4 a1 = *reinterpret_cast<const float4*>(np + 4);
    float4 a2 = *reinterpret_cast<const float4*>(np + 8);
    float4 a3 = *reinterpret_cast<const float4*>(np + 12);
    float4 a4 = *reinterpret_cast<const float4*>(np + 16);
    float4 a5 = *reinterpret_cast<const float4*>(np + 20);
    float4 a6 = *reinterpret_cast<const float4*>(np + 24);
    float4 a7 = *reinterpret_cast<const float4*>(np + 28);
#pragma unroll
    for (int o = 0; o < 8; ++o) {
      const float* wo = w + (og + o) * 64;
      float y = base[o];
      y = fmaf(wo[0],  a0.x, y); y = fmaf(wo[1],  a0.y, y); y = fmaf(wo[2],  a0.z, y); y = fmaf(wo[3],  a0.w, y);
      y = fmaf(wo[4],  a1.x, y); y = fmaf(wo[5],  a1.y, y); y = fmaf(wo[6],  a1.z, y); y = fmaf(wo[7],  a1.w, y);
      y = fmaf(wo[8],  a2.x, y); y = fmaf(wo[9],  a2.y, y); y = fmaf(wo[10], a2.z, y); y = fmaf(wo[11], a2.w, y);
      y = fmaf(wo[12], a3.x, y); y = fmaf(wo[13], a3.y, y); y = fmaf(wo[14], a3.z, y); y = fmaf(wo[15], a3.w, y);
      y = fmaf(wo[16], a4.x, y); y = fmaf(wo[17], a4.y, y); y = fmaf(wo[18], a4.z, y); y = fmaf(wo[19], a4.w, y);
      y = fmaf(wo[20], a5.x, y); y = fmaf(wo[21], a5.y, y); y = fmaf(wo[22], a5.z, y); y = fmaf(wo[23], a5.w, y);
      y = fmaf(wo[24], a6.x, y); y = fmaf(wo[25], a6.y, y); y = fmaf(wo[26], a6.z, y); y = fmaf(wo[27], a6.w, y);
      y = fmaf(wo[28], a7.x, y); y = fmaf(wo[29], a7.y, y); y = fmaf(wo[30], a7.z, y); y = fmaf(wo[31], a7.w, y);
      mx[o] = fmaxf(mx[o], lrelu(y * bnp[og + o] + bnp[32 + og + o]));
    }
  }
#pragma unroll
  for (int o = 0; o < 8; ++o) xd2[(size_t)bn * 32 + og + o] = mx[o];
}

// ---------------- reshape-mean: hm[b][j] = mean_{c<64,t<64} h[b][c][t*64+j] ----------------
__global__ void k_mean(const float* __restrict__ xd1, const float* __restrict__ xd2,
                       float* __restrict__ hm) {
  int b = blockIdx.x >> 6, j = blockIdx.x & 63;
  int tt = threadIdx.x;
  const float* p1 = xd1 + ((size_t)(b * NP) + tt * 64 + j) * 32;
  const float* p2 = xd2 + ((size_t)(b * NP) + tt * 64 + j) * 32;
  float s = 0.f;
#pragma unroll
  for (int c = 0; c < 32; c += 4) {
    float4 a = *reinterpret_cast<const float4*>(p1 + c);
    s += a.x + a.y + a.z + a.w;
  }
#pragma unroll
  for (int c = 0; c < 32; c += 4) {
    float4 a = *reinterpret_cast<const float4*>(p2 + c);
    s += a.x + a.y + a.z + a.w;
  }
#pragma unroll
  for (int off = 32; off >= 1; off >>= 1) s += __shfl_xor(s, off);
  if (tt == 0) hm[blockIdx.x] = s * (1.f / 4096.f);
}

// ---------------- tiny MLP head ----------------
__global__ void k_mlp(const float* __restrict__ hm,
                      const float* __restrict__ w1, const float* __restrict__ b1,
                      const float* __restrict__ w2, const float* __restrict__ b2,
                      const float* __restrict__ w3, const float* __restrict__ b3,
                      float* __restrict__ out) {
  __shared__ float h0[512], h1[512], h2[256];
  int t = threadIdx.x;
  h0[t] = hm[t];
  __syncthreads();
  {
    int b = t >> 6, o = t & 63;
    float a = b1[o];
    for (int j = 0; j < 64; ++j) a += h0[b * 64 + j] * w1[o * 64 + j];
    h1[t] = lrelu(a);
  }
  __syncthreads();
  if (t < 256) {
    int b = t >> 5, o = t & 31;
    float a = b2[o];
    for (int j = 0; j < 64; ++j) a += h1[b * 64 + j] * w2[o * 64 + j];
    h2[t] = lrelu(a);
  }
  __syncthreads();
  if (t < 88) {
    int b = t / 11, o = t % 11;
    float a = b3[o];
    for (int j = 0; j < 32; ++j) a += h2[b * 32 + j] * w3[o * 32 + j];
    out[t] = lrelu(a);
  }
}

// ---------------- launch ----------------
extern "C" void kernel_launch(void* const* d_in, const int* in_sizes, int n_in,
                              void* d_out, int out_size, void* d_ws, size_t ws_size,
                              hipStream_t stream) {
  const float* xin = (const float*)d_in[0];
  const float* w1  = (const float*)d_in[1];
  const float* g1  = (const float*)d_in[2];
  const float* bb1 = (const float*)d_in[3];
  const float* w2  = (const float*)d_in[4];
  const float* g2  = (const float*)d_in[5];
  const float* bb2 = (const float*)d_in[6];
  const float* wd1 = (const float*)d_in[7];
  const float* gd1 = (const float*)d_in[8];
  const float* bbd1= (const float*)d_in[9];
  const float* wd2 = (const float*)d_in[10];
  const float* gd2 = (const float*)d_in[11];
  const float* bbd2= (const float*)d_in[12];
  const float* l1w = (const float*)d_in[13];
  const float* l1b = (const float*)d_in[14];
  const float* l2w = (const float*)d_in[15];
  const float* l2b = (const float*)d_in[16];
  const float* l3w = (const float*)d_in[17];
  const float* l3b = (const float*)d_in[18];
  float* out = (float*)d_out;

  float* W = (float*)d_ws;
  float* xt    = W;                       // 131072
  float* xx1   = W + 131072;              // 32768
  float* xx2   = W + 163840;              // 32768
  float* xx3   = W + 196608;              // 32768
  float* x1m   = W + 229376;              // 524288
  float* x2m   = W + 753664;              // 1048576
  float* xd1   = W + 1802240;             // 1048576
  float* xd2   = W + 2850816;             // 1048576
  float* hmean = W + 3899392;             // 512
  float* bnp1  = W + 3899904;             // 64
  float* bnp2  = W + 3899968;             // 64
  float* bnpd1 = W + 3900032;             // 64
  float* bnpd2 = W + 3900096;             // 64
  float* parts = W + 3900160;             // 32768
  int* idx1 = (int*)(W + 3932928);        // 655360 ints
  int* idx2 = idx1 + 655360;
  int* idx3 = idx2 + 655360;
  // transposed copies alias xd1/xd2: consumed by knn16/knn32, which complete
  // before applyd1/applyd2 overwrite these regions (same-stream ordering).
  float* x1mT = xd1;                      // 524288 needed <= 1048576
  float* x2mT = xd2;                      // 1048576 needed

  k_prep<<<128, 256, 0, stream>>>(xin, xt, xx1);
  k_knn<4, 1024, false><<<8192, 256, 0, stream>>>(xt, xt, xx1, idx1);

  k_stats1<<<dim3(128, 1, 2), 256, 0, stream>>>(xt, idx1, w1, parts);
  k_bnfin<16, 16, 1, 2><<<1, 256, 0, stream>>>(parts, g1, bb1, bnp1);
  k_apply1<<<dim3(128, 2), 256, 0, stream>>>(xt, idx1, w1, bnp1, x1m, x1mT);
  k_xx<16><<<128, 256, 0, stream>>>(x1m, xx2);
  k_knn<16, 256, true><<<16384, 256, 0, stream>>>(x1m, x1mT, xx2, idx2);

  k_stats2<<<dim3(128, 4, 2), 256, 0, stream>>>(xt, x1m, idx1, idx2, w2, parts);
  k_bnfin<32, 8, 4, 2><<<1, 256, 0, stream>>>(parts, g2, bb2, bnp2);
  k_apply2<<<dim3(128, 4), 256, 0, stream>>>(xt, x1m, idx1, idx2, w2, bnp2, x2m, x2mT);
  k_xx<32><<<128, 256, 0, stream>>>(x2m, xx3);

  k_statsd1<<<dim3(128, 4, 2), 256, 0, stream>>>(x1m, idx2, wd1, parts);
  k_bnfin<32, 8, 4, 2><<<1, 256, 0, stream>>>(parts, gd1, bbd1, bnpd1);
  k_applyd1<<<dim3(128, 4), 256, 0, stream>>>(x1m, idx2, wd1, bnpd1, xd1);

  k_knn<32, 128, true><<<16384, 256, 0, stream>>>(x2m, x2mT, xx3, idx3);
  k_statsd2<<<dim3(128, 4, 2), 256, 0, stream>>>(x2m, idx3, wd2, parts);
  k_bnfin<32, 8, 4, 2><<<1, 256, 0, stream>>>(parts, gd2, bbd2, bnpd2);
  k_applyd2<<<dim3(128, 4), 256, 0, stream>>>(x2m, idx3, wd2, bnpd2, xd2);

  k_mean<<<512, 64, 0, stream>>>(xd1, xd2, hmean);
  k_mlp<<<1, 512, 0, stream>>>(hmean, l1w, l1b, l2w, l2b, l3w, l3b, out);
}

// Round 15
// 1562.832 us; speedup vs baseline: 1.3494x; 1.3494x over previous
//
#include <hip/hip_runtime.h>
#include <cstddef>

#define DI __device__ __forceinline__

constexpr int NB  = 8;
constexpr int NP  = 4096;
constexpr int KNN = 20;

DI float lrelu(float z) { return z >= 0.f ? z : 0.2f * z; }

// ---------------- prep: transpose input to point-major xt[b][n][4] + xx ----------------
__global__ void k_prep(const float* __restrict__ xin, float* __restrict__ xt,
                       float* __restrict__ xx) {
  int t = blockIdx.x * blockDim.x + threadIdx.x;           // bn
  int b = t >> 12, n = t & (NP - 1);
  float c0 = xin[(0 * NB + b) * NP + n];
  float c1 = xin[(1 * NB + b) * NP + n];
  float c2 = xin[(2 * NB + b) * NP + n];
  *reinterpret_cast<float4*>(xt + (size_t)t * 4) = make_float4(c0, c1, c2, 0.f);
  xx[t] = c0 * c0 + c1 * c1 + c2 * c2;
}

// ---------------- xx for C-channel point-major ----------------
template<int C>
__global__ void k_xx(const float* __restrict__ X, float* __restrict__ xx) {
  int bn = blockIdx.x * blockDim.x + threadIdx.x;
  float s = 0.f;
#pragma unroll
  for (int c = 0; c < C; c += 4) {
    float4 a = *reinterpret_cast<const float4*>(X + (size_t)bn * C + c);
    s += a.x * a.x + a.y * a.y + a.z * a.z + a.w * a.w;
  }
  xx[bn] = s;
}

// ---------------- knn v4 (round-11/13 proven): plane-major candidates ----------
// one wave per row, 4 rows/block; P points/chunk (P*F4 == 1024 => LD=4).
// staging: global read linear in XT (coalesced), LDS write lds4[u] linear,
// distance read B[cg*P + p] lane-contiguous  -> all in the measured 0-conflict class.
template<int C, int P>
__global__ __launch_bounds__(256) void k_knn(const float* __restrict__ Xq,
                                             const float* __restrict__ XT,
                                             const float* __restrict__ xx,
                                             int* __restrict__ idxout) {
  constexpr int CH = NP / P;                // chunks
  constexpr int SL = P / 64;                // slots per chunk
  constexpr int F4 = C / 4;                 // float4 per point
  constexpr int LD = P * F4 / 256;          // staging float4 loads per thread (=4)
  __shared__ float4 lds4[2 * P * F4];

  int wv   = threadIdx.x >> 6;
  int lane = threadIdx.x & 63;
  int row  = blockIdx.x * 4 + wv;
  int b = row >> 12, n = row & (NP - 1);
  const float*  Xqb  = Xq + (size_t)b * NP * C;
  const float4* srcT = reinterpret_cast<const float4*>(XT + (size_t)b * NP * C);
  const float*  xxb  = xx + (size_t)b * NP;

  float q[C];
#pragma unroll
  for (int c = 0; c < C; c += 4) {
    float4 a = *reinterpret_cast<const float4*>(Xqb + (size_t)n * C + c);
    q[c] = a.x; q[c + 1] = a.y; q[c + 2] = a.z; q[c + 3] = a.w;
  }
  float xxn = xxb[n];

  float v[64];
  float gv[4]; int gj[4];
#pragma unroll
  for (int g = 0; g < 4; ++g) { gv[g] = -3.0e38f; gj[g] = 0; }

  // prologue: prefetch chunk 0 (plane u/P, point u%P)
  float4 nxt[LD];
#pragma unroll
  for (int i = 0; i < LD; ++i) {
    int u = i * 256 + (int)threadIdx.x;
    nxt[i] = srcT[(size_t)(u / P) * NP + (u % P)];
  }

#pragma unroll
  for (int ch = 0; ch < CH; ++ch) {
    float4* B = lds4 + (ch & 1) * (P * F4);
#pragma unroll
    for (int i = 0; i < LD; ++i)
      B[i * 256 + (int)threadIdx.x] = nxt[i];   // linear, stride-1 writes
    __syncthreads();                        // all writes to buf[ch&1] visible
    if (ch + 1 < CH) {                      // issue next chunk AFTER barrier
#pragma unroll
      for (int i = 0; i < LD; ++i) {
        int u = i * 256 + (int)threadIdx.x;
        nxt[i] = srcT[(size_t)(u / P) * NP + (size_t)(ch + 1) * P + (u % P)];
      }
    }
#pragma unroll
    for (int sl = 0; sl < SL; ++sl) {
      const int s = ch * SL + sl;           // global slot (compile-time)
      int p = sl * 64 + lane;
      float xxm = xxb[s * 64 + lane];
      float dp[4] = {0.f, 0.f, 0.f, 0.f};
#pragma unroll
      for (int cg = 0; cg < F4; ++cg) {
        float4 a = B[cg * P + p];           // lane-contiguous reads
        dp[cg & 3] = fmaf(q[cg * 4 + 0], a.x, dp[cg & 3]);
        dp[cg & 3] = fmaf(q[cg * 4 + 1], a.y, dp[cg & 3]);
        dp[cg & 3] = fmaf(q[cg * 4 + 2], a.z, dp[cg & 3]);
        dp[cg & 3] = fmaf(q[cg * 4 + 3], a.w, dp[cg & 3]);
      }
      float dot = (dp[0] + dp[1]) + (dp[2] + dp[3]);
      float val = 2.f * dot - xxm - xxn;    // pd = 2*dot - xxm - xxn
      v[s] = val;
      const int g = s >> 4;                 // compile-time
      bool better = val > gv[g];            // strict > : earliest slot wins ties
      gv[g] = better ? val : gv[g];
      gj[g] = better ? s   : gj[g];
    }
    // single barrier per chunk: writes to this buffer (iter ch+2) can only start
    // after all waves passed barrier(ch+1), i.e. after compute(ch) finished.
  }

  int gi[4];
#pragma unroll
  for (int g = 0; g < 4; ++g) gi[g] = (gj[g] << 6) | lane;   // global index

  int myidx = 0;
#pragma unroll 1
  for (int t = 0; t < KNN; ++t) {
    float bv = gv[0]; int bi = gi[0];
#pragma unroll
    for (int g = 1; g < 4; ++g) {
      bool bet = gv[g] > bv;
      bv = bet ? gv[g] : bv;
      bi = bet ? gi[g] : bi;
    }
#pragma unroll
    for (int off = 32; off >= 1; off >>= 1) {
      float ov = __shfl_xor(bv, off);
      int   oi = __shfl_xor(bi, off);
      bool bet = (ov > bv) || (ov == bv && oi < bi);
      bv = bet ? ov : bv;
      bi = bet ? oi : bi;
    }
    if (lane == t) myidx = bi;
    if (lane == (bi & 63)) {
      int jw = bi >> 6;
      int g  = jw >> 4;
#pragma unroll
      for (int G = 0; G < 4; ++G) {
        if (g == G) {
          float nv = -3.0e38f; int nj = 0;
#pragma unroll
          for (int jj = G * 16; jj < G * 16 + 16; ++jj) {
            v[jj] = (jj == jw) ? -3.4e38f : v[jj];
            bool bet = v[jj] > nv;
            nv = bet ? v[jj] : nv;
            nj = bet ? jj : nj;
          }
          gv[G] = nv;
          gi[G] = (nj << 6) | lane;
        }
      }
    }
  }
  if (lane < KNN) idxout[(size_t)row * KNN + lane] = myidx;
}

// ---------------- deterministic block reduce: CG channels of (s,ss) ----------------
template<int CG>
DI void block_reduce_write(float (&s)[CG], float (&ss)[CG], float* red, float* out) {
#pragma unroll
  for (int o = 0; o < CG; ++o) {
#pragma unroll
    for (int off = 32; off >= 1; off >>= 1) {
      s[o]  += __shfl_xor(s[o],  off);
      ss[o] += __shfl_xor(ss[o], off);
    }
  }
  int lane = threadIdx.x & 63, wv = threadIdx.x >> 6;
  if (lane == 0) {
#pragma unroll
    for (int o = 0; o < CG; ++o) {
      red[wv * 2 * CG + o]      = s[o];
      red[wv * 2 * CG + CG + o] = ss[o];
    }
  }
  __syncthreads();
  if ((int)threadIdx.x < 2 * CG) {
    out[threadIdx.x] = red[0 * 2 * CG + threadIdx.x] + red[1 * 2 * CG + threadIdx.x] +
                       red[2 * 2 * CG + threadIdx.x] + red[3 * 2 * CG + threadIdx.x];
  }
}

// ---------------- BN finalize (parallel, deterministic) ----------------
template<int COUT, int CG, int OG, int KG>
__global__ void k_bnfin(const float* __restrict__ parts, const float* __restrict__ g,
                        const float* __restrict__ bb, float* __restrict__ bnp) {
  constexpr int G = 256 / COUT;
  __shared__ float red[512];
  int tid = threadIdx.x;
  int sub = tid / COUT, o = tid % COUT;
  int og = o / CG, oo = o % CG;
  float S = 0.f, SS = 0.f;
  for (int z = 0; z < KG; ++z)
    for (int x = sub; x < 128; x += G) {
      size_t p = ((size_t)(z * OG + og) * 128 + x) * (2 * CG);
      S  += parts[p + oo];
      SS += parts[p + CG + oo];
    }
  red[tid] = S; red[256 + tid] = SS;
  __syncthreads();
  if (tid < COUT) {
    S = 0.f; SS = 0.f;
#pragma unroll
    for (int gg = 0; gg < G; ++gg) { S += red[gg * COUT + tid]; SS += red[256 + gg * COUT + tid]; }
    const float cnt = (float)NB * NP * KNN;
    float m   = S / cnt;
    float var = SS / cnt - m * m;
    float sc  = g[tid] / sqrtf(var + 1e-5f);
    bnp[tid]        = sc;
    bnp[COUT + tid] = bb[tid] - m * sc;
  }
}

// ================= conv1: Cin=6, Cout=16 (all 16 ch/block, base trick) =================
__global__ __launch_bounds__(256) void k_stats1(const float* __restrict__ xt,
    const int* __restrict__ idx1, const float* __restrict__ w, float* __restrict__ parts) {
  __shared__ float red[4 * 32];
  int bn = blockIdx.x * 256 + threadIdx.x;
  int b = bn >> 12;
  float4 ctr = *reinterpret_cast<const float4*>(xt + (size_t)bn * 4);
  float base[16], s[16], ss[16];
#pragma unroll
  for (int o = 0; o < 16; ++o) {
    const float* wo = w + o * 6;
    base[o] = (wo[3] - wo[0]) * ctr.x + (wo[4] - wo[1]) * ctr.y + (wo[5] - wo[2]) * ctr.z;
    s[o] = 0.f; ss[o] = 0.f;
  }
  const int* ip = idx1 + (size_t)bn * KNN + blockIdx.z * 10;
  for (int kk = 0; kk < 10; ++kk) {
    int m = ip[kk];
    float4 nb = *reinterpret_cast<const float4*>(xt + (size_t)(b * NP + m) * 4);
#pragma unroll
    for (int o = 0; o < 16; ++o) {
      const float* wo = w + o * 6;
      float y = fmaf(wo[0], nb.x, fmaf(wo[1], nb.y, fmaf(wo[2], nb.z, base[o])));
      s[o] += y; ss[o] = fmaf(y, y, ss[o]);
    }
  }
  size_t p = ((size_t)blockIdx.z * 128 + blockIdx.x) * 32;
  block_reduce_write<16>(s, ss, red, parts + p);
}

// apply1 also writes plane-major x1mT (fused transpose)
__global__ __launch_bounds__(256) void k_apply1(const float* __restrict__ xt,
    const int* __restrict__ idx1, const float* __restrict__ w, const float* __restrict__ bnp,
    float* __restrict__ x1m, float* __restrict__ x1mT) {
  int bn = blockIdx.x * 256 + threadIdx.x;
  int og = blockIdx.y * 8;
  int b = bn >> 12, pidx = bn & (NP - 1);
  float4 ctr = *reinterpret_cast<const float4*>(xt + (size_t)bn * 4);
  float base[8], mx[8];
#pragma unroll
  for (int o = 0; o < 8; ++o) {
    const float* wo = w + (og + o) * 6;
    base[o] = (wo[3] - wo[0]) * ctr.x + (wo[4] - wo[1]) * ctr.y + (wo[5] - wo[2]) * ctr.z;
    mx[o] = -3.0e38f;
  }
  const int* ip = idx1 + (size_t)bn * KNN;
  for (int k = 0; k < KNN; ++k) {
    int m = ip[k];
    float4 nb = *reinterpret_cast<const float4*>(xt + (size_t)(b * NP + m) * 4);
#pragma unroll
    for (int o = 0; o < 8; ++o) {
      const float* wo = w + (og + o) * 6;
      float y = fmaf(wo[0], nb.x, fmaf(wo[1], nb.y, fmaf(wo[2], nb.z, base[o])));
      mx[o] = fmaxf(mx[o], lrelu(y * bnp[og + o] + bnp[16 + og + o]));
    }
  }
#pragma unroll
  for (int o = 0; o < 8; ++o) x1m[(size_t)bn * 16 + og + o] = mx[o];
  int cg0 = og >> 2;
  float4 lo = make_float4(mx[0], mx[1], mx[2], mx[3]);
  float4 hi = make_float4(mx[4], mx[5], mx[6], mx[7]);
  reinterpret_cast<float4*>(x1mT)[(size_t)b * NP * 4 + (size_t)cg0 * NP + pidx] = lo;
  reinterpret_cast<float4*>(x1mT)[(size_t)b * NP * 4 + (size_t)(cg0 + 1) * NP + pidx] = hi;
}

// ================= conv2: Cin=38, Cout=32, CG=8 =================
__global__ __launch_bounds__(256) void k_stats2(const float* __restrict__ xt,
    const float* __restrict__ x1m, const int* __restrict__ idx1, const int* __restrict__ idx2,
    const float* __restrict__ w, float* __restrict__ parts) {
  __shared__ float red[4 * 16];
  int bn = blockIdx.x * 256 + threadIdx.x;
  int og = blockIdx.y * 8;
  int b = bn >> 12;
  float4 ctr3 = *reinterpret_cast<const float4*>(xt + (size_t)bn * 4);
  float base[8], s[8], ss[8];
#pragma unroll
  for (int o = 0; o < 8; ++o) {
    const float* wo = w + (og + o) * 38;
    base[o] = (wo[3] - wo[0]) * ctr3.x + (wo[4] - wo[1]) * ctr3.y + (wo[5] - wo[2]) * ctr3.z;
    s[o] = 0.f; ss[o] = 0.f;
  }
#pragma unroll
  for (int cg = 0; cg < 4; ++cg) {
    float4 a = *reinterpret_cast<const float4*>(x1m + (size_t)bn * 16 + cg * 4);
#pragma unroll
    for (int o = 0; o < 8; ++o) {
      const float* wo = w + (og + o) * 38;
      base[o] += (wo[22 + cg*4] - wo[6 + cg*4]) * a.x + (wo[23 + cg*4] - wo[7 + cg*4]) * a.y +
                 (wo[24 + cg*4] - wo[8 + cg*4]) * a.z + (wo[25 + cg*4] - wo[9 + cg*4]) * a.w;
    }
  }
  const int* i1 = idx1 + (size_t)bn * KNN + blockIdx.z * 10;
  const int* i2 = idx2 + (size_t)bn * KNN + blockIdx.z * 10;
  for (int kk = 0; kk < 10; ++kk) {
    int m1 = i1[kk], m2 = i2[kk];
    float4 nb3 = *reinterpret_cast<const float4*>(xt + (size_t)(b * NP + m1) * 4);
    float4 a0 = *reinterpret_cast<const float4*>(x1m + (size_t)(b * NP + m2) * 16 + 0);
    float4 a1 = *reinterpret_cast<const float4*>(x1m + (size_t)(b * NP + m2) * 16 + 4);
    float4 a2 = *reinterpret_cast<const float4*>(x1m + (size_t)(b * NP + m2) * 16 + 8);
    float4 a3 = *reinterpret_cast<const float4*>(x1m + (size_t)(b * NP + m2) * 16 + 12);
#pragma unroll
    for (int o = 0; o < 8; ++o) {
      const float* wo = w + (og + o) * 38;
      float y = base[o];
      y = fmaf(wo[0], nb3.x, y); y = fmaf(wo[1], nb3.y, y); y = fmaf(wo[2], nb3.z, y);
      y = fmaf(wo[6],  a0.x, y); y = fmaf(wo[7],  a0.y, y); y = fmaf(wo[8],  a0.z, y); y = fmaf(wo[9],  a0.w, y);
      y = fmaf(wo[10], a1.x, y); y = fmaf(wo[11], a1.y, y); y = fmaf(wo[12], a1.z, y); y = fmaf(wo[13], a1.w, y);
      y = fmaf(wo[14], a2.x, y); y = fmaf(wo[15], a2.y, y); y = fmaf(wo[16], a2.z, y); y = fmaf(wo[17], a2.w, y);
      y = fmaf(wo[18], a3.x, y); y = fmaf(wo[19], a3.y, y); y = fmaf(wo[20], a3.z, y); y = fmaf(wo[21], a3.w, y);
      s[o] += y; ss[o] = fmaf(y, y, ss[o]);
    }
  }
  size_t p = ((size_t)(blockIdx.z * 4 + blockIdx.y) * 128 + blockIdx.x) * 16;
  block_reduce_write<8>(s, ss, red, parts + p);
}

// apply2 also writes plane-major x2mT (fused transpose)
__global__ __launch_bounds__(256) void k_apply2(const float* __restrict__ xt,
    const float* __restrict__ x1m, const int* __restrict__ idx1, const int* __restrict__ idx2,
    const float* __restrict__ w, const float* __restrict__ bnp, float* __restrict__ x2m,
    float* __restrict__ x2mT) {
  int bn = blockIdx.x * 256 + threadIdx.x;
  int og = blockIdx.y * 8;
  int b = bn >> 12, pidx = bn & (NP - 1);
  float4 ctr3 = *reinterpret_cast<const float4*>(xt + (size_t)bn * 4);
  float base[8], mx[8];
#pragma unroll
  for (int o = 0; o < 8; ++o) {
    const float* wo = w + (og + o) * 38;
    base[o] = (wo[3] - wo[0]) * ctr3.x + (wo[4] - wo[1]) * ctr3.y + (wo[5] - wo[2]) * ctr3.z;
    mx[o] = -3.0e38f;
  }
#pragma unroll
  for (int cg = 0; cg < 4; ++cg) {
    float4 a = *reinterpret_cast<const float4*>(x1m + (size_t)bn * 16 + cg * 4);
#pragma unroll
    for (int o = 0; o < 8; ++o) {
      const float* wo = w + (og + o) * 38;
      base[o] += (wo[22 + cg*4] - wo[6 + cg*4]) * a.x + (wo[23 + cg*4] - wo[7 + cg*4]) * a.y +
                 (wo[24 + cg*4] - wo[8 + cg*4]) * a.z + (wo[25 + cg*4] - wo[9 + cg*4]) * a.w;
    }
  }
  const int* i1 = idx1 + (size_t)bn * KNN;
  const int* i2 = idx2 + (size_t)bn * KNN;
  for (int k = 0; k < KNN; ++k) {
    int m1 = i1[k], m2 = i2[k];
    float4 nb3 = *reinterpret_cast<const float4*>(xt + (size_t)(b * NP + m1) * 4);
    float4 a0 = *reinterpret_cast<const float4*>(x1m + (size_t)(b * NP + m2) * 16 + 0);
    float4 a1 = *reinterpret_cast<const float4*>(x1m + (size_t)(b * NP + m2) * 16 + 4);
    float4 a2 = *reinterpret_cast<const float4*>(x1m + (size_t)(b * NP + m2) * 16 + 8);
    float4 a3 = *reinterpret_cast<const float4*>(x1m + (size_t)(b * NP + m2) * 16 + 12);
#pragma unroll
    for (int o = 0; o < 8; ++o) {
      const float* wo = w + (og + o) * 38;
      float y = base[o];
      y = fmaf(wo[0], nb3.x, y); y = fmaf(wo[1], nb3.y, y); y = fmaf(wo[2], nb3.z, y);
      y = fmaf(wo[6],  a0.x, y); y = fmaf(wo[7],  a0.y, y); y = fmaf(wo[8],  a0.z, y); y = fmaf(wo[9],  a0.w, y);
      y = fmaf(wo[10], a1.x, y); y = fmaf(wo[11], a1.y, y); y = fmaf(wo[12], a1.z, y); y = fmaf(wo[13], a1.w, y);
      y = fmaf(wo[14], a2.x, y); y = fmaf(wo[15], a2.y, y); y = fmaf(wo[16], a2.z, y); y = fmaf(wo[17], a2.w, y);
      y = fmaf(wo[18], a3.x, y); y = fmaf(wo[19], a3.y, y); y = fmaf(wo[20], a3.z, y); y = fmaf(wo[21], a3.w, y);
      mx[o] = fmaxf(mx[o], lrelu(y * bnp[og + o] + bnp[32 + og + o]));
    }
  }
#pragma unroll
  for (int o = 0; o < 8; ++o) x2m[(size_t)bn * 32 + og + o] = mx[o];
  int cg0 = og >> 2;
  float4 lo = make_float4(mx[0], mx[1], mx[2], mx[3]);
  float4 hi = make_float4(mx[4], mx[5], mx[6], mx[7]);
  reinterpret_cast<float4*>(x2mT)[(size_t)b * NP * 8 + (size_t)cg0 * NP + pidx] = lo;
  reinterpret_cast<float4*>(x2mT)[(size_t)b * NP * 8 + (size_t)(cg0 + 1) * NP + pidx] = hi;
}

// ================= convd1: Cin=32 (x1m/idx2), Cout=32, CG=8 =================
__global__ __launch_bounds__(256) void k_statsd1(const float* __restrict__ x1m,
    const int* __restrict__ idx2, const float* __restrict__ w, float* __restrict__ parts) {
  __shared__ float red[4 * 16];
  int bn = blockIdx.x * 256 + threadIdx.x;
  int og = blockIdx.y * 8;
  int b = bn >> 12;
  float base[8], s[8], ss[8];
#pragma unroll
  for (int o = 0; o < 8; ++o) { base[o] = 0.f; s[o] = 0.f; ss[o] = 0.f; }
#pragma unroll
  for (int cg = 0; cg < 4; ++cg) {
    float4 a = *reinterpret_cast<const float4*>(x1m + (size_t)bn * 16 + cg * 4);
#pragma unroll
    for (int o = 0; o < 8; ++o) {
      const float* wo = w + (og + o) * 32;
      base[o] += (wo[16 + cg*4] - wo[cg*4]) * a.x + (wo[17 + cg*4] - wo[1 + cg*4]) * a.y +
                 (wo[18 + cg*4] - wo[2 + cg*4]) * a.z + (wo[19 + cg*4] - wo[3 + cg*4]) * a.w;
    }
  }
  const int* i2 = idx2 + (size_t)bn * KNN + blockIdx.z * 10;
  for (int kk = 0; kk < 10; ++kk) {
    int m2 = i2[kk];
    float4 a0 = *reinterpret_cast<const float4*>(x1m + (size_t)(b * NP + m2) * 16 + 0);
    float4 a1 = *reinterpret_cast<const float4*>(x1m + (size_t)(b * NP + m2) * 16 + 4);
    float4 a2 = *reinterpret_cast<const float4*>(x1m + (size_t)(b * NP + m2) * 16 + 8);
    float4 a3 = *reinterpret_cast<const float4*>(x1m + (size_t)(b * NP + m2) * 16 + 12);
#pragma unroll
    for (int o = 0; o < 8; ++o) {
      const float* wo = w + (og + o) * 32;
      float y = base[o];
      y = fmaf(wo[0],  a0.x, y); y = fmaf(wo[1],  a0.y, y); y = fmaf(wo[2],  a0.z, y); y = fmaf(wo[3],  a0.w, y);
      y = fmaf(wo[4],  a1.x, y); y = fmaf(wo[5],  a1.y, y); y = fmaf(wo[6],  a1.z, y); y = fmaf(wo[7],  a1.w, y);
      y = fmaf(wo[8],  a2.x, y); y = fmaf(wo[9],  a2.y, y); y = fmaf(wo[10], a2.z, y); y = fmaf(wo[11], a2.w, y);
      y = fmaf(wo[12], a3.x, y); y = fmaf(wo[13], a3.y, y); y = fmaf(wo[14], a3.z, y); y = fmaf(wo[15], a3.w, y);
      s[o] += y; ss[o] = fmaf(y, y, ss[o]);
    }
  }
  size_t p = ((size_t)(blockIdx.z * 4 + blockIdx.y) * 128 + blockIdx.x) * 16;
  block_reduce_write<8>(s, ss, red, parts + p);
}

__global__ __launch_bounds__(256) void k_applyd1(const float* __restrict__ x1m,
    const int* __restrict__ idx2, const float* __restrict__ w, const float* __restrict__ bnp,
    float* __restrict__ xd1) {
  int bn = blockIdx.x * 256 + threadIdx.x;
  int og = blockIdx.y * 8;
  int b = bn >> 12;
  float base[8], mx[8];
#pragma unroll
  for (int o = 0; o < 8; ++o) { base[o] = 0.f; mx[o] = -3.0e38f; }
#pragma unroll
  for (int cg = 0; cg < 4; ++cg) {
    float4 a = *reinterpret_cast<const float4*>(x1m + (size_t)bn * 16 + cg * 4);
#pragma unroll
    for (int o = 0; o < 8; ++o) {
      const float* wo = w + (og + o) * 32;
      base[o] += (wo[16 + cg*4] - wo[cg*4]) * a.x + (wo[17 + cg*4] - wo[1 + cg*4]) * a.y +
                 (wo[18 + cg*4] - wo[2 + cg*4]) * a.z + (wo[19 + cg*4] - wo[3 + cg*4]) * a.w;
    }
  }
  const int* i2 = idx2 + (size_t)bn * KNN;
  for (int k = 0; k < KNN; ++k) {
    int m2 = i2[k];
    float4 a0 = *reinterpret_cast<const float4*>(x1m + (size_t)(b * NP + m2) * 16 + 0);
    float4 a1 = *reinterpret_cast<const float4*>(x1m + (size_t)(b * NP + m2) * 16 + 4);
    float4 a2 = *reinterpret_cast<const float4*>(x1m + (size_t)(b * NP + m2) * 16 + 8);
    float4 a3 = *reinterpret_cast<const float4*>(x1m + (size_t)(b * NP + m2) * 16 + 12);
#pragma unroll
    for (int o = 0; o < 8; ++o) {
      const float* wo = w + (og + o) * 32;
      float y = base[o];
      y = fmaf(wo[0],  a0.x, y); y = fmaf(wo[1],  a0.y, y); y = fmaf(wo[2],  a0.z, y); y = fmaf(wo[3],  a0.w, y);
      y = fmaf(wo[4],  a1.x, y); y = fmaf(wo[5],  a1.y, y); y = fmaf(wo[6],  a1.z, y); y = fmaf(wo[7],  a1.w, y);
      y = fmaf(wo[8],  a2.x, y); y = fmaf(wo[9],  a2.y, y); y = fmaf(wo[10], a2.z, y); y = fmaf(wo[11], a2.w, y);
      y = fmaf(wo[12], a3.x, y); y = fmaf(wo[13], a3.y, y); y = fmaf(wo[14], a3.z, y); y = fmaf(wo[15], a3.w, y);
      mx[o] = fmaxf(mx[o], lrelu(y * bnp[og + o] + bnp[32 + og + o]));
    }
  }
#pragma unroll
  for (int o = 0; o < 8; ++o) xd1[(size_t)bn * 32 + og + o] = mx[o];
}

// ================= convd2: Cin=64 (x2m/idx3), Cout=32, CG=8 =================
__global__ __launch_bounds__(256) void k_statsd2(const float* __restrict__ x2m,
    const int* __restrict__ idx3, const float* __restrict__ w, float* __restrict__ parts) {
  __shared__ float red[4 * 16];
  int bn = blockIdx.x * 256 + threadIdx.x;
  int og = blockIdx.y * 8;
  int b = bn >> 12;
  float base[8], s[8], ss[8];
#pragma unroll
  for (int o = 0; o < 8; ++o) { base[o] = 0.f; s[o] = 0.f; ss[o] = 0.f; }
#pragma unroll
  for (int cg = 0; cg < 8; ++cg) {
    float4 a = *reinterpret_cast<const float4*>(x2m + (size_t)bn * 32 + cg * 4);
#pragma unroll
    for (int o = 0; o < 8; ++o) {
      const float* wo = w + (og + o) * 64;
      base[o] += (wo[32 + cg*4] - wo[cg*4]) * a.x + (wo[33 + cg*4] - wo[1 + cg*4]) * a.y +
                 (wo[34 + cg*4] - wo[2 + cg*4]) * a.z + (wo[35 + cg*4] - wo[3 + cg*4]) * a.w;
    }
  }
  const int* i3 = idx3 + (size_t)bn * KNN + blockIdx.z * 10;
  for (int kk = 0; kk < 10; ++kk) {
    int m3 = i3[kk];
    const float* np = x2m + (size_t)(b * NP + m3) * 32;
    float4 a0 = *reinterpret_cast<const float4*>(np + 0);
    float4 a1 = *reinterpret_cast<const float4*>(np + 4);
    float4 a2 = *reinterpret_cast<const float4*>(np + 8);
    float4 a3 = *reinterpret_cast<const float4*>(np + 12);
    float4 a4 = *reinterpret_cast<const float4*>(np + 16);
    float4 a5 = *reinterpret_cast<const float4*>(np + 20);
    float4 a6 = *reinterpret_cast<const float4*>(np + 24);
    float4 a7 = *reinterpret_cast<const float4*>(np + 28);
#pragma unroll
    for (int o = 0; o < 8; ++o) {
      const float* wo = w + (og + o) * 64;
      float y = base[o];
      y = fmaf(wo[0],  a0.x, y); y = fmaf(wo[1],  a0.y, y); y = fmaf(wo[2],  a0.z, y); y = fmaf(wo[3],  a0.w, y);
      y = fmaf(wo[4],  a1.x, y); y = fmaf(wo[5],  a1.y, y); y = fmaf(wo[6],  a1.z, y); y = fmaf(wo[7],  a1.w, y);
      y = fmaf(wo[8],  a2.x, y); y = fmaf(wo[9],  a2.y, y); y = fmaf(wo[10], a2.z, y); y = fmaf(wo[11], a2.w, y);
      y = fmaf(wo[12], a3.x, y); y = fmaf(wo[13], a3.y, y); y = fmaf(wo[14], a3.z, y); y = fmaf(wo[15], a3.w, y);
      y = fmaf(wo[16], a4.x, y); y = fmaf(wo[17], a4.y, y); y = fmaf(wo[18], a4.z, y); y = fmaf(wo[19], a4.w, y);
      y = fmaf(wo[20], a5.x, y); y = fmaf(wo[21], a5.y, y); y = fmaf(wo[22], a5.z, y); y = fmaf(wo[23], a5.w, y);
      y = fmaf(wo[24], a6.x, y); y = fmaf(wo[25], a6.y, y); y = fmaf(wo[26], a6.z, y); y = fmaf(wo[27], a6.w, y);
      y = fmaf(wo[28], a7.x, y); y = fmaf(wo[29], a7.y, y); y = fmaf(wo[30], a7.z, y); y = fmaf(wo[31], a7.w, y);
      s[o] += y; ss[o] = fmaf(y, y, ss[o]);
    }
  }
  size_t p = ((size_t)(blockIdx.z * 4 + blockIdx.y) * 128 + blockIdx.x) * 16;
  block_reduce_write<8>(s, ss, red, parts + p);
}

__global__ __launch_bounds__(256) void k_applyd2(const float* __restrict__ x2m,
    const int* __restrict__ idx3, const float* __restrict__ w, const float* __restrict__ bnp,
    float* __restrict__ xd2) {
  int bn = blockIdx.x * 256 + threadIdx.x;
  int og = blockIdx.y * 8;
  int b = bn >> 12;
  float base[8], mx[8];
#pragma unroll
  for (int o = 0; o < 8; ++o) { base[o] = 0.f; mx[o] = -3.0e38f; }
#pragma unroll
  for (int cg = 0; cg < 8; ++cg) {
    float4 a = *reinterpret_cast<const float4*>(x2m + (size_t)bn * 32 + cg * 4);
#pragma unroll
    for (int o = 0; o < 8; ++o) {
      const float* wo = w + (og + o) * 64;
      base[o] += (wo[32 + cg*4] - wo[cg*4]) * a.x + (wo[33 + cg*4] - wo[1 + cg*4]) * a.y +
                 (wo[34 + cg*4] - wo[2 + cg*4]) * a.z + (wo[35 + cg*4] - wo[3 + cg*4]) * a.w;
    }
  }
  const int* i3 = idx3 + (size_t)bn * KNN;
  for (int k = 0; k < KNN; ++k) {
    int m3 = i3[k];
    const float* np = x2m + (size_t)(b * NP + m3) * 32;
    float4 a0 = *reinterpret_cast<const float4*>(np + 0);
    float4 a1 = *reinterpret_cast<const float4*>(np + 4);
    float4 a2 = *reinterpret_cast<const float4*>(np + 8);
    float4 a3 = *reinterpret_cast<const float4*>(np + 12);
    float4 a4 = *reinterpret_cast<const float4*>(np + 16);
    float4 a5 = *reinterpret_cast<const float4*>(np + 20);
    float4 a6 = *reinterpret_cast<const float4*>(np + 24);
    float4 a7 = *reinterpret_cast<const float4*>(np + 28);
#pragma unroll
    for (int o = 0; o < 8; ++o) {
      const float* wo = w + (og + o) * 64;
      float y = base[o];
      y = fmaf(wo[0],  a0.x, y); y = fmaf(wo[1],  a0.y, y); y = fmaf(wo[2],  a0.z, y); y = fmaf(wo[3],  a0.w, y);
      y = fmaf(wo[4],  a1.x, y); y = fmaf(wo[5],  a1.y, y); y = fmaf(wo[6],  a1.z, y); y = fmaf(wo[7],  a1.w, y);
      y = fmaf(wo[8],  a2.x, y); y = fmaf(wo[9],  a2.y, y); y = fmaf(wo[10], a2.z, y); y = fmaf(wo[11], a2.w, y);
      y = fmaf(wo[12], a3.x, y); y = fmaf(wo[13], a3.y, y); y = fmaf(wo[14], a3.z, y); y = fmaf(wo[15], a3.w, y);
      y = fmaf(wo[16], a4.x, y); y = fmaf(wo[17], a4.y, y); y = fmaf(wo[18], a4.z, y); y = fmaf(wo[19], a4.w, y);
      y = fmaf(wo[20], a5.x, y); y = fmaf(wo[21], a5.y, y); y = fmaf(wo[22], a5.z, y); y = fmaf(wo[23], a5.w, y);
      y = fmaf(wo[24], a6.x, y); y = fmaf(wo[25], a6.y, y); y = fmaf(wo[26], a6.z, y); y = fmaf(wo[27], a6.w, y);
      y = fmaf(wo[28], a7.x, y); y = fmaf(wo[29], a7.y, y); y = fmaf(wo[30], a7.z, y); y = fmaf(wo[31], a7.w, y);
      mx[o] = fmaxf(mx[o], lrelu(y * bnp[og + o] + bnp[32 + og + o]));
    }
  }
#pragma unroll
  for (int o = 0; o < 8; ++o) xd2[(size_t)bn * 32 + og + o] = mx[o];
}

// ---------------- reshape-mean: hm[b][j] = mean_{c<64,t<64} h[b][c][t*64+j] ----------------
__global__ void k_mean(const float* __restrict__ xd1, const float* __restrict__ xd2,
                       float* __restrict__ hm) {
  int b = blockIdx.x >> 6, j = blockIdx.x & 63;
  int tt = threadIdx.x;
  const float* p1 = xd1 + ((size_t)(b * NP) + tt * 64 + j) * 32;
  const float* p2 = xd2 + ((size_t)(b * NP) + tt * 64 + j) * 32;
  float s = 0.f;
#pragma unroll
  for (int c = 0; c < 32; c += 4) {
    float4 a = *reinterpret_cast<const float4*>(p1 + c);
    s += a.x + a.y + a.z + a.w;
  }
#pragma unroll
  for (int c = 0; c < 32; c += 4) {
    float4 a = *reinterpret_cast<const float4*>(p2 + c);
    s += a.x + a.y + a.z + a.w;
  }
#pragma unroll
  for (int off = 32; off >= 1; off >>= 1) s += __shfl_xor(s, off);
  if (tt == 0) hm[blockIdx.x] = s * (1.f / 4096.f);
}

// ---------------- tiny MLP head ----------------
__global__ void k_mlp(const float* __restrict__ hm,
                      const float* __restrict__ w1, const float* __restrict__ b1,
                      const float* __restrict__ w2, const float* __restrict__ b2,
                      const float* __restrict__ w3, const float* __restrict__ b3,
                      float* __restrict__ out) {
  __shared__ float h0[512], h1[512], h2[256];
  int t = threadIdx.x;
  h0[t] = hm[t];
  __syncthreads();
  {
    int b = t >> 6, o = t & 63;
    float a = b1[o];
    for (int j = 0; j < 64; ++j) a += h0[b * 64 + j] * w1[o * 64 + j];
    h1[t] = lrelu(a);
  }
  __syncthreads();
  if (t < 256) {
    int b = t >> 5, o = t & 31;
    float a = b2[o];
    for (int j = 0; j < 64; ++j) a += h1[b * 64 + j] * w2[o * 64 + j];
    h2[t] = lrelu(a);
  }
  __syncthreads();
  if (t < 88) {
    int b = t / 11, o = t % 11;
    float a = b3[o];
    for (int j = 0; j < 32; ++j) a += h2[b * 32 + j] * w3[o * 32 + j];
    out[t] = lrelu(a);
  }
}

// ---------------- launch ----------------
extern "C" void kernel_launch(void* const* d_in, const int* in_sizes, int n_in,
                              void* d_out, int out_size, void* d_ws, size_t ws_size,
                              hipStream_t stream) {
  const float* xin = (const float*)d_in[0];
  const float* w1  = (const float*)d_in[1];
  const float* g1  = (const float*)d_in[2];
  const float* bb1 = (const float*)d_in[3];
  const float* w2  = (const float*)d_in[4];
  const float* g2  = (const float*)d_in[5];
  const float* bb2 = (const float*)d_in[6];
  const float* wd1 = (const float*)d_in[7];
  const float* gd1 = (const float*)d_in[8];
  const float* bbd1= (const float*)d_in[9];
  const float* wd2 = (const float*)d_in[10];
  const float* gd2 = (const float*)d_in[11];
  const float* bbd2= (const float*)d_in[12];
  const float* l1w = (const float*)d_in[13];
  const float* l1b = (const float*)d_in[14];
  const float* l2w = (const float*)d_in[15];
  const float* l2b = (const float*)d_in[16];
  const float* l3w = (const float*)d_in[17];
  const float* l3b = (const float*)d_in[18];
  float* out = (float*)d_out;

  float* W = (float*)d_ws;
  float* xt    = W;                       // 131072
  float* xx1   = W + 131072;              // 32768
  float* xx2   = W + 163840;              // 32768
  float* xx3   = W + 196608;              // 32768
  float* x1m   = W + 229376;              // 524288
  float* x2m   = W + 753664;              // 1048576
  float* xd1   = W + 1802240;             // 1048576
  float* xd2   = W + 2850816;             // 1048576
  float* hmean = W + 3899392;             // 512
  float* bnp1  = W + 3899904;             // 64
  float* bnp2  = W + 3899968;             // 64
  float* bnpd1 = W + 3900032;             // 64
  float* bnpd2 = W + 3900096;             // 64
  float* parts = W + 3900160;             // 32768
  int* idx1 = (int*)(W + 3932928);        // 655360 ints
  int* idx2 = idx1 + 655360;
  int* idx3 = idx2 + 655360;
  // transposed copies alias xd1/xd2: consumed by knn16/knn32, which complete
  // before applyd1/applyd2 overwrite these regions (same-stream ordering).
  float* x1mT = xd1;                      // 524288 needed <= 1048576
  float* x2mT = xd2;                      // 1048576 needed

  k_prep<<<128, 256, 0, stream>>>(xin, xt, xx1);
  k_knn<4, 1024><<<8192, 256, 0, stream>>>(xt, xt, xx1, idx1);

  k_stats1<<<dim3(128, 1, 2), 256, 0, stream>>>(xt, idx1, w1, parts);
  k_bnfin<16, 16, 1, 2><<<1, 256, 0, stream>>>(parts, g1, bb1, bnp1);
  k_apply1<<<dim3(128, 2), 256, 0, stream>>>(xt, idx1, w1, bnp1, x1m, x1mT);
  k_xx<16><<<128, 256, 0, stream>>>(x1m, xx2);
  k_knn<16, 256><<<8192, 256, 0, stream>>>(x1m, x1mT, xx2, idx2);

  k_stats2<<<dim3(128, 4, 2), 256, 0, stream>>>(xt, x1m, idx1, idx2, w2, parts);
  k_bnfin<32, 8, 4, 2><<<1, 256, 0, stream>>>(parts, g2, bb2, bnp2);
  k_apply2<<<dim3(128, 4), 256, 0, stream>>>(xt, x1m, idx1, idx2, w2, bnp2, x2m, x2mT);
  k_xx<32><<<128, 256, 0, stream>>>(x2m, xx3);

  k_statsd1<<<dim3(128, 4, 2), 256, 0, stream>>>(x1m, idx2, wd1, parts);
  k_bnfin<32, 8, 4, 2><<<1, 256, 0, stream>>>(parts, gd1, bbd1, bnpd1);
  k_applyd1<<<dim3(128, 4), 256, 0, stream>>>(x1m, idx2, wd1, bnpd1, xd1);

  k_knn<32, 128><<<8192, 256, 0, stream>>>(x2m, x2mT, xx3, idx3);
  k_statsd2<<<dim3(128, 4, 2), 256, 0, stream>>>(x2m, idx3, wd2, parts);
  k_bnfin<32, 8, 4, 2><<<1, 256, 0, stream>>>(parts, gd2, bbd2, bnpd2);
  k_applyd2<<<dim3(128, 4), 256, 0, stream>>>(x2m, idx3, wd2, bnpd2, xd2);

  k_mean<<<512, 64, 0, stream>>>(xd1, xd2, hmean);
  k_mlp<<<1, 512, 0, stream>>>(hmean, l1w, l1b, l2w, l2b, l3w, l3b, out);
}